// Round 1
// baseline (32.431 us; speedup 1.0000x reference)
//
#include <hip/hip_runtime.h>

// Problem: BeamCTCDecoder — degenerate beam search == per-step argmax, then CTC collapse.
// logits: (N=128, C=128, T=2048) float32, layout n*C*T + c*T + t.
// out: (N, T) int32 — collapsed tokens, blank(0)-padded.

constexpr int N = 128;
constexpr int C = 128;
constexpr int T = 2048;

// ---------------- Kernel A: per-(n,t) argmax over classes ----------------
// Each thread owns 4 consecutive t's (float4 loads). Grid = N*T/4 threads.
// log-softmax is monotone per (n,t), so argmax over raw logits matches reference.
__global__ __launch_bounds__(256) void argmax_kernel(const float* __restrict__ logits,
                                                     int* __restrict__ tokens) {
    const int gid = blockIdx.x * blockDim.x + threadIdx.x;   // 0 .. N*T/4-1
    const int n  = gid / (T / 4);
    const int t4 = (gid % (T / 4)) * 4;
    const float* base = logits + (size_t)n * C * T + t4;

    float4 best = *(const float4*)(base);                    // c = 0
    int4 bidx = make_int4(0, 0, 0, 0);
    #pragma unroll 4
    for (int c = 1; c < C; ++c) {
        float4 v = *(const float4*)(base + (size_t)c * T);
        // strict > keeps the FIRST max (matches jnp.argmax tie-break)
        if (v.x > best.x) { best.x = v.x; bidx.x = c; }
        if (v.y > best.y) { best.y = v.y; bidx.y = c; }
        if (v.z > best.z) { best.z = v.z; bidx.z = c; }
        if (v.w > best.w) { best.w = v.w; bidx.w = c; }
    }
    *(int4*)(tokens + (size_t)n * T + t4) = bidx;
}

// ---------------- Kernel B: per-row CTC collapse ----------------
// One block (256 threads) per row n; each thread owns 8 consecutive t's.
// keep = (tok != 0) && (tok != prev). Block-wide exclusive scan of keep
// counts -> compacted scatter; row zero-filled first.
__global__ __launch_bounds__(256) void collapse_kernel(const int* __restrict__ tokens,
                                                       int* __restrict__ out) {
    const int n = blockIdx.x;
    const int* trow = tokens + (size_t)n * T;
    int* orow = out + (size_t)n * T;
    const int tid = threadIdx.x;            // 0..255
    constexpr int PER = T / 256;            // 8
    const int t0 = tid * PER;

    int tok[PER];
    *(int4*)&tok[0] = *(const int4*)(trow + t0);
    *(int4*)&tok[4] = *(const int4*)(trow + t0 + 4);
    int prev = (t0 == 0) ? -1 : trow[t0 - 1];

    // thread-local keep flags & compacted offsets
    int kpos[PER];
    int cnt = 0;
    #pragma unroll
    for (int i = 0; i < PER; ++i) {
        const bool k = (tok[i] != 0) && (tok[i] != prev);
        kpos[i] = k ? cnt : -1;
        cnt += k ? 1 : 0;
        prev = tok[i];
    }

    // wave-level (64-lane!) inclusive scan of cnt
    const int lane = tid & 63;
    const int wid  = tid >> 6;              // 0..3
    int incl = cnt;
    #pragma unroll
    for (int d = 1; d < 64; d <<= 1) {
        int v = __shfl_up(incl, d, 64);
        if (lane >= d) incl += v;
    }

    __shared__ int wsum[4];
    if (lane == 63) wsum[wid] = incl;

    // zero-fill the output row (before the barrier; scatter happens after)
    const int4 z = make_int4(0, 0, 0, 0);
    *(int4*)(orow + t0)     = z;
    *(int4*)(orow + t0 + 4) = z;

    __syncthreads();   // orders zero-fill + wsum before scatter/read

    int wbase = 0;
    #pragma unroll
    for (int w = 0; w < 4; ++w)
        if (w < wid) wbase += wsum[w];
    const int base = wbase + (incl - cnt);  // exclusive prefix for this thread

    #pragma unroll
    for (int i = 0; i < PER; ++i) {
        if (kpos[i] >= 0) orow[base + kpos[i]] = tok[i];
    }
}

extern "C" void kernel_launch(void* const* d_in, const int* in_sizes, int n_in,
                              void* d_out, int out_size, void* d_ws, size_t ws_size,
                              hipStream_t stream) {
    const float* logits = (const float*)d_in[0];
    int* out = (int*)d_out;
    int* tokens = (int*)d_ws;               // N*T int32 = 1 MiB scratch

    const int threadsA = 256;
    const int gridA = (N * T / 4) / threadsA;   // 256 blocks
    argmax_kernel<<<gridA, threadsA, 0, stream>>>(logits, tokens);
    collapse_kernel<<<N, 256, 0, stream>>>(tokens, out);
}

// Round 2
// 27.436 us; speedup vs baseline: 1.1821x; 1.1821x over previous
//
#include <hip/hip_runtime.h>

// BeamCTCDecoder — degenerate beam search == per-step argmax, then CTC collapse.
// logits: (N=128, C=128, T=2048) float32, layout n*C*T + c*T + t.
// out: (N, T) int32 — collapsed tokens, blank(0)-padded.

constexpr int N = 128;
constexpr int C = 128;
constexpr int T = 2048;

// ---------------- Kernel A: per-(n,t) argmax over classes, 2-way c-split ----------------
// Block = 256 threads: threads 0-127 scan c in [0,64), threads 128-255 scan
// c in [64,128) for the SAME 128 t-quads; combine via LDS. 512 blocks ->
// 8 waves/CU (2/SIMD) for latency hiding; unroll 8 -> 8 KiB in flight/wave.
__global__ __launch_bounds__(256) void argmax_kernel(const float* __restrict__ logits,
                                                     int* __restrict__ tokens) {
    __shared__ float sbest[128][4];
    __shared__ int   sidx[128][4];

    const int tid  = threadIdx.x;
    const int tq   = tid & 127;          // t-quad slot within block
    const int half = tid >> 7;           // 0: c 0..63, 1: c 64..127
    const int blk  = blockIdx.x;
    const int n    = blk >> 2;           // 4 blocks per row
    const int t4   = ((blk & 3) * 128 + tq) * 4;

    const float* base = logits + (size_t)n * C * T + (size_t)(half * 64) * T + t4;

    float4 best = *(const float4*)(base);               // local c = 0
    int4 bidx = make_int4(0, 0, 0, 0);
    #pragma unroll 8
    for (int c = 1; c < 64; ++c) {
        float4 v = *(const float4*)(base + (size_t)c * T);
        // strict > keeps the FIRST max (matches jnp.argmax tie-break)
        if (v.x > best.x) { best.x = v.x; bidx.x = c; }
        if (v.y > best.y) { best.y = v.y; bidx.y = c; }
        if (v.z > best.z) { best.z = v.z; bidx.z = c; }
        if (v.w > best.w) { best.w = v.w; bidx.w = c; }
    }

    if (half) {                                         // upper half: publish
        sbest[tq][0] = best.x; sbest[tq][1] = best.y;
        sbest[tq][2] = best.z; sbest[tq][3] = best.w;
        sidx[tq][0] = bidx.x + 64; sidx[tq][1] = bidx.y + 64;
        sidx[tq][2] = bidx.z + 64; sidx[tq][3] = bidx.w + 64;
    }
    __syncthreads();
    if (!half) {                                        // lower half: combine + write
        // upper wins only on strict > -> ties keep the lower class index
        if (sbest[tq][0] > best.x) bidx.x = sidx[tq][0];
        if (sbest[tq][1] > best.y) bidx.y = sidx[tq][1];
        if (sbest[tq][2] > best.z) bidx.z = sidx[tq][2];
        if (sbest[tq][3] > best.w) bidx.w = sidx[tq][3];
        *(int4*)(tokens + (size_t)n * T + t4) = bidx;
    }
}

// ---------------- Kernel B: per-row CTC collapse ----------------
// One block (256 threads) per row n; each thread owns 8 consecutive t's.
__global__ __launch_bounds__(256) void collapse_kernel(const int* __restrict__ tokens,
                                                       int* __restrict__ out) {
    const int n = blockIdx.x;
    const int* trow = tokens + (size_t)n * T;
    int* orow = out + (size_t)n * T;
    const int tid = threadIdx.x;            // 0..255
    constexpr int PER = T / 256;            // 8
    const int t0 = tid * PER;

    int tok[PER];
    *(int4*)&tok[0] = *(const int4*)(trow + t0);
    *(int4*)&tok[4] = *(const int4*)(trow + t0 + 4);
    int prev = (t0 == 0) ? -1 : trow[t0 - 1];

    int kpos[PER];
    int cnt = 0;
    #pragma unroll
    for (int i = 0; i < PER; ++i) {
        const bool k = (tok[i] != 0) && (tok[i] != prev);
        kpos[i] = k ? cnt : -1;
        cnt += k ? 1 : 0;
        prev = tok[i];
    }

    // wave-level (64-lane) inclusive scan of per-thread counts
    const int lane = tid & 63;
    const int wid  = tid >> 6;              // 0..3
    int incl = cnt;
    #pragma unroll
    for (int d = 1; d < 64; d <<= 1) {
        int v = __shfl_up(incl, d, 64);
        if (lane >= d) incl += v;
    }

    __shared__ int wsum[4];
    if (lane == 63) wsum[wid] = incl;

    // zero-fill the output row before the barrier; scatter after
    const int4 z = make_int4(0, 0, 0, 0);
    *(int4*)(orow + t0)     = z;
    *(int4*)(orow + t0 + 4) = z;

    __syncthreads();

    int wbase = 0;
    #pragma unroll
    for (int w = 0; w < 4; ++w)
        if (w < wid) wbase += wsum[w];
    const int base = wbase + (incl - cnt);  // exclusive prefix for this thread

    #pragma unroll
    for (int i = 0; i < PER; ++i) {
        if (kpos[i] >= 0) orow[base + kpos[i]] = tok[i];
    }
}

extern "C" void kernel_launch(void* const* d_in, const int* in_sizes, int n_in,
                              void* d_out, int out_size, void* d_ws, size_t ws_size,
                              hipStream_t stream) {
    const float* logits = (const float*)d_in[0];
    int* out = (int*)d_out;
    int* tokens = (int*)d_ws;               // N*T int32 = 1 MiB scratch

    const int gridA = N * 4;                // 4 blocks per row, 512 total
    argmax_kernel<<<gridA, 256, 0, stream>>>(logits, tokens);
    collapse_kernel<<<N, 256, 0, stream>>>(tokens, out);
}